// Round 10
// baseline (540.947 us; speedup 1.0000x reference)
//
#include <hip/hip_runtime.h>
#include <hip/hip_bf16.h>

// ---------------- problem constants ----------------
#define B_    256
#define T_    250
#define NIN   700
#define NHID  512
#define NOUT  20
#define KT_N  11                 // k-tiles of 64 per segment: 704 = 11*64
#define M_TOT (B_ * T_)          // 64000

typedef float  f32x2  __attribute__((ext_vector_type(2)));
typedef float  f32x4  __attribute__((ext_vector_type(4)));
typedef float  f32x16 __attribute__((ext_vector_type(16)));
typedef int    i32x2  __attribute__((ext_vector_type(2)));
typedef int    i32x4  __attribute__((ext_vector_type(4)));
typedef int    i32x8  __attribute__((ext_vector_type(8)));

// ---------------- workspace layout ----------------
// [0, 65,536,000)   : i_in  (M_TOT x NHID bf16)
// [+, 1,441,792)    : Bpack fp8 fragment-major (4 segs)
// [+, 1,048,576)    : w_recT (512x512 f32)
// total ~68 MB
#define IIN_BYTES   ((size_t)M_TOT * NHID * 2)
#define BPACK_OFF   IIN_BYTES
#define BPACK_BYTES ((size_t)4 * KT_N * 16 * 64 * 32)
#define BPACK_WORDS (BPACK_BYTES / 4)                  // 360,448
#define WRECT_OFF   (BPACK_OFF + BPACK_BYTES)
#define BSEG        (KT_N * 16 * 512)                  // 90,112 words per B seg

// ---------------- kernel 1: pack B to fp8 fragment-major + transpose w_rec ----------------
__global__ __launch_bounds__(256) void kan_pack(
    const float* __restrict__ w_kan, const float* __restrict__ d1,
    const float* __restrict__ d2,    const float* __restrict__ d3,
    const float* __restrict__ w_rec,
    int* __restrict__ BpackW, float* __restrict__ wrecT)
{
    int idx = blockIdx.x * 256 + threadIdx.x;
    if (idx < (int)BPACK_WORDS) {
        int w   = idx;
        int c   = w >> 3;                  // 32-byte chunk index
        int jj  = (w & 7) * 4;             // byte offset within chunk
        int ln  = c & 31;
        int kh  = (c >> 5) & 1;
        int nt  = (c >> 6) & 15;
        int ks  = c >> 10;                 // seg*11 + kt
        int kt  = ks % 11;
        int seg = ks / 11;
        int n   = nt * 32 + ln;
        int kb  = kt * 64 + kh * 32 + jj;
        const float* wp = (seg == 0) ? w_kan : (seg == 1) ? d1 : (seg == 2) ? d2 : d3;
        float f0 = (kb + 0 < NIN) ? wp[(size_t)n * NIN + kb + 0] : 0.0f;
        float f1 = (kb + 1 < NIN) ? wp[(size_t)n * NIN + kb + 1] : 0.0f;
        float f2 = (kb + 2 < NIN) ? wp[(size_t)n * NIN + kb + 2] : 0.0f;
        float f3 = (kb + 3 < NIN) ? wp[(size_t)n * NIN + kb + 3] : 0.0f;
        int u = __builtin_amdgcn_cvt_pk_fp8_f32(f0, f1, 0, false);
        u     = __builtin_amdgcn_cvt_pk_fp8_f32(f2, f3, u, true);
        BpackW[w] = u;
    }
    if (idx < NHID * NHID) {
        int h  = idx & 511;
        int hp = idx >> 9;
        wrecT[(size_t)hp * NHID + h] = w_rec[(size_t)h * NHID + hp];
    }
}

// ---- pack 16 f32 -> 16 fp8 bytes (4 words) ----
__device__ __forceinline__ i32x4 pack16(const float* s) {
    i32x4 w;
    #pragma unroll
    for (int j = 0; j < 4; ++j) {
        int u = __builtin_amdgcn_cvt_pk_fp8_f32(s[4 * j + 0], s[4 * j + 1], 0, false);
        u     = __builtin_amdgcn_cvt_pk_fp8_f32(s[4 * j + 2], s[4 * j + 3], u, true);
        w[j] = u;
    }
    return w;
}

// ---- convert 16 x-values -> 4 seg fragments, store to LDS (sequential to cap regs) ----
__device__ __forceinline__ void conv_store(const float* e, int* dst) {
    *(i32x4*)(dst + 0) = pack16(e);                    // seg0: raw x
    float p1[16];
    #pragma unroll
    for (int i = 0; i < 16; ++i) p1[i] = fminf(fabsf(e[i]), 1.0f);
    *(i32x4*)(dst + 512) = pack16(p1);                 // seg1: t1
    float p2[16];
    #pragma unroll
    for (int i = 0; i < 16; ++i) p2[i] = p1[i] * p1[i];
    *(i32x4*)(dst + 1024) = pack16(p2);                // seg2: t1^2
    float p3[16];
    #pragma unroll
    for (int i = 0; i < 16; ++i) p3[i] = p2[i] * p1[i];
    *(i32x4*)(dst + 1536) = pack16(p3);                // seg3: t1^3
}

// ---------------- kernel 2: FUSED x->fp8 + GEMM (R6 base + latency fixes) ----------------
// R8 post-mortem: single-wave ILP failed (13% MfmaUtil, B thrashed HBM). Revert to
// R6 (best: 142us @ 26% MfmaUtil). R6's residual stalls: (a) per-seg JIT B loads
// exposed ~200cy L2 latency 4x/kt (VGPR=128 cap left no prefetch room), (b) the
// ~500cy convert VALU sat AFTER all MFMAs, serialized. This round, R6 unchanged
// except the kt loop: x/B(s0,s1) loads issue BEFORE the barrier (raw s_barrier +
// lgkmcnt-only wait keeps them in flight -- no vmcnt drain), B(s2)/B(s3) issued
// one seg ahead (rolling register prefetch; fits the 256-reg budget of (512,2)),
// and convert+ds_write sits between seg1 and seg2 where it fills the MFMA shadow.
// (R9 bench was an infra failure -- container acquisition -- resubmitted as-is.)
__global__ __launch_bounds__(512, 2) void kan_gemm(
    const float* __restrict__ x, const int* __restrict__ Bpack,
    __bf16* __restrict__ iin)
{
    __shared__ int lds[2][8192];              // 2 x 32 KB: 4 mc-chunks x 4 segs x 512 words

    const int tid  = threadIdx.x;
    const int lane = tid & 63;
    const int wn   = tid >> 6;       // wave 0..7 : 64-col group
    const int by   = blockIdx.x;     // 0..499 : 128-row tile
    const int l31  = lane & 31;
    const int kh   = lane >> 5;

    // conversion mapping: thread t = mcL*128 + q2*32 + r31 (r fastest -> conflict-free)
    const int r31v = tid & 31;
    const int q2   = (tid >> 5) & 3;
    const int mcL  = tid >> 7;       // 0..3
    const int xrow = by * 128 + mcL * 32 + r31v;
    const float* xr = x + (size_t)xrow * NIN;
    const int kf    = q2 * 16;
    const int wbase = mcL * 2048 + (q2 & 1) * 256 + (q2 >> 1) * 128 + r31v * 4;

    f32x16 acc[4][2];
    #pragma unroll
    for (int c = 0; c < 4; ++c)
        #pragma unroll
        for (int j = 0; j < 2; ++j)
            #pragma unroll
            for (int r = 0; r < 16; ++r)
                acc[c][j][r] = 0.0f;

    // ---- prologue: load+convert kt=0 into buf 0 (barrier happens at loop top) ----
    {
        float e[16];
        #pragma unroll
        for (int c = 0; c < 4; ++c) {
            int k = kf + c * 4;                // kt=0: always < 700
            f32x4 v = *(const f32x4*)(xr + k);
            e[c * 4 + 0] = v[0]; e[c * 4 + 1] = v[1];
            e[c * 4 + 2] = v[2]; e[c * 4 + 3] = v[3];
        }
        conv_store(e, &lds[0][wbase]);
    }

    int buf = 0;
    #pragma unroll 1
    for (int kt = 0; kt < KT_N; ++kt) {
        const bool more = (kt + 1 < KT_N);

        // ---- issue x loads for kt+1 (in flight across the barrier) ----
        f32x4 xv[4];
        #pragma unroll
        for (int c = 0; c < 4; ++c) {
            int k = (kt + 1) * 64 + kf + c * 4;
            xv[c] = (more && k < NIN) ? *(const f32x4*)(xr + k)
                                      : f32x4{0.f, 0.f, 0.f, 0.f};
        }
        // ---- issue B seg0/seg1 for this kt (also ride across the barrier) ----
        const int* bb = Bpack + (size_t)(kt * 16 + wn * 2) * 512 + lane * 8;
        i32x8 b00 = *(const i32x8*)(bb);
        i32x8 b01 = *(const i32x8*)(bb + 512);
        i32x8 b10 = *(const i32x8*)(bb + BSEG);
        i32x8 b11 = *(const i32x8*)(bb + BSEG + 512);
        __builtin_amdgcn_sched_barrier(0);

        // ---- barrier: prev iter's LDS traffic done; vmem stays outstanding ----
        asm volatile("s_waitcnt lgkmcnt(0)" ::: "memory");
        __builtin_amdgcn_s_barrier();
        __builtin_amdgcn_sched_barrier(0);

        // ---- seg 0 ----
        #pragma unroll
        for (int c = 0; c < 4; ++c) {
            const int* ab = &lds[buf][(c * 4 + 0) * 512 + lane * 4];
            i32x4 lo = *(const i32x4*)ab;
            i32x4 hi = *(const i32x4*)(ab + 256);
            i32x8 A = i32x8{lo[0], lo[1], lo[2], lo[3], hi[0], hi[1], hi[2], hi[3]};
            acc[c][0] = __builtin_amdgcn_mfma_scale_f32_32x32x64_f8f6f4(
                A, b00, acc[c][0], 0, 0, 0, 0x7f7f7f7f, 0, 0x7f7f7f7f);
            acc[c][1] = __builtin_amdgcn_mfma_scale_f32_32x32x64_f8f6f4(
                A, b01, acc[c][1], 0, 0, 0, 0x7f7f7f7f, 0, 0x7f7f7f7f);
        }
        // prefetch B seg2 (retires under seg1's MFMAs)
        i32x8 b20 = *(const i32x8*)(bb + 2 * BSEG);
        i32x8 b21 = *(const i32x8*)(bb + 2 * BSEG + 512);

        // ---- seg 1 ----
        #pragma unroll
        for (int c = 0; c < 4; ++c) {
            const int* ab = &lds[buf][(c * 4 + 1) * 512 + lane * 4];
            i32x4 lo = *(const i32x4*)ab;
            i32x4 hi = *(const i32x4*)(ab + 256);
            i32x8 A = i32x8{lo[0], lo[1], lo[2], lo[3], hi[0], hi[1], hi[2], hi[3]};
            acc[c][0] = __builtin_amdgcn_mfma_scale_f32_32x32x64_f8f6f4(
                A, b10, acc[c][0], 0, 0, 0, 0x7f7f7f7f, 0, 0x7f7f7f7f);
            acc[c][1] = __builtin_amdgcn_mfma_scale_f32_32x32x64_f8f6f4(
                A, b11, acc[c][1], 0, 0, 0, 0x7f7f7f7f, 0, 0x7f7f7f7f);
        }
        // prefetch B seg3
        i32x8 b30 = *(const i32x8*)(bb + 3 * BSEG);
        i32x8 b31 = *(const i32x8*)(bb + 3 * BSEG + 512);
        __builtin_amdgcn_sched_barrier(0);   // convert may not hoist above this point

        // ---- convert kt+1 -> LDS[buf^1]; VALU interleaves under seg2/3 MFMAs ----
        if (more) {
            float e[16];
            #pragma unroll
            for (int c = 0; c < 4; ++c) {
                e[c * 4 + 0] = xv[c][0]; e[c * 4 + 1] = xv[c][1];
                e[c * 4 + 2] = xv[c][2]; e[c * 4 + 3] = xv[c][3];
            }
            conv_store(e, &lds[buf ^ 1][wbase]);
        }

        // ---- seg 2 ----
        #pragma unroll
        for (int c = 0; c < 4; ++c) {
            const int* ab = &lds[buf][(c * 4 + 2) * 512 + lane * 4];
            i32x4 lo = *(const i32x4*)ab;
            i32x4 hi = *(const i32x4*)(ab + 256);
            i32x8 A = i32x8{lo[0], lo[1], lo[2], lo[3], hi[0], hi[1], hi[2], hi[3]};
            acc[c][0] = __builtin_amdgcn_mfma_scale_f32_32x32x64_f8f6f4(
                A, b20, acc[c][0], 0, 0, 0, 0x7f7f7f7f, 0, 0x7f7f7f7f);
            acc[c][1] = __builtin_amdgcn_mfma_scale_f32_32x32x64_f8f6f4(
                A, b21, acc[c][1], 0, 0, 0, 0x7f7f7f7f, 0, 0x7f7f7f7f);
        }
        // ---- seg 3 ----
        #pragma unroll
        for (int c = 0; c < 4; ++c) {
            const int* ab = &lds[buf][(c * 4 + 3) * 512 + lane * 4];
            i32x4 lo = *(const i32x4*)ab;
            i32x4 hi = *(const i32x4*)(ab + 256);
            i32x8 A = i32x8{lo[0], lo[1], lo[2], lo[3], hi[0], hi[1], hi[2], hi[3]};
            acc[c][0] = __builtin_amdgcn_mfma_scale_f32_32x32x64_f8f6f4(
                A, b30, acc[c][0], 0, 0, 0, 0x7f7f7f7f, 0, 0x7f7f7f7f);
            acc[c][1] = __builtin_amdgcn_mfma_scale_f32_32x32x64_f8f6f4(
                A, b31, acc[c][1], 0, 0, 0, 0x7f7f7f7f, 0, 0x7f7f7f7f);
        }
        buf ^= 1;
    }

    // ---- epilogue: 32x32 C/D layout col=lane&31, row=(r&3)+8*(r>>2)+4*(lane>>5) ----
    #pragma unroll
    for (int c = 0; c < 4; ++c) {
        int m0 = by * 128 + c * 32 + kh * 4;
        #pragma unroll
        for (int j = 0; j < 2; ++j) {
            int col = wn * 64 + j * 32 + l31;
            #pragma unroll
            for (int r = 0; r < 16; ++r) {
                int row = m0 + (r & 3) + 8 * (r >> 2);
                iin[(size_t)row * NHID + col] = (__bf16)acc[c][j][r];
            }
        }
    }
}

// ---------------- kernel 3: adaptive-LIF scan, one wave per sample, PF=25 bf16 ----------------
#define PF 25
__global__ __launch_bounds__(64) void kan_scan(
    const __bf16* __restrict__ iin, const float* __restrict__ wrecT,
    const float* __restrict__ w_out, float* __restrict__ out)
{
    const int b    = blockIdx.x;
    const int lane = threadIdx.x;
    const __bf16* basep = iin + (size_t)b * T_ * NHID + lane * 8;
    #define LOADQ(t) (*(const i32x4*)(basep + (size_t)(t) * NHID))

    i32x4 q[PF];
    #pragma unroll
    for (int d = 0; d < PF; ++d) q[d] = LOADQ(d);

    float v1[8], a1[8];
    #pragma unroll
    for (int u = 0; u < 8; ++u) { v1[u] = 0.f; a1[u] = 0.f; }
    unsigned sm = 0;
    int anyprev = 0;
    float v_out = 0.f, acco = 0.f;

    #pragma unroll 1
    for (int t0 = 0; t0 < T_; t0 += PF) {
        #pragma unroll
        for (int j = 0; j < PF; ++j) {
            const int t = t0 + j;
            float cur[8];
            #pragma unroll
            for (int w = 0; w < 4; ++w) {
                int wv = q[j][w];
                cur[2 * w]     = __builtin_bit_cast(float, wv << 16);
                cur[2 * w + 1] = __builtin_bit_cast(float, wv & 0xffff0000);
            }
            if (t + PF < T_) q[j] = LOADQ(t + PF);

            if (anyprev) {           // rare path: recurrent input from prev spikes
                #pragma unroll
                for (int u = 0; u < 8; ++u) {
                    unsigned long long mu = __ballot((sm >> u) & 1u);
                    while (mu) {
                        int jl = __ffsll(mu) - 1; mu &= mu - 1;
                        const float* wr = wrecT + (size_t)(jl * 8 + u) * NHID + lane * 8;
                        f32x4 wa = *(const f32x4*)wr;
                        f32x4 wb = *(const f32x4*)(wr + 4);
                        cur[0] += wa[0]; cur[1] += wa[1]; cur[2] += wa[2]; cur[3] += wa[3];
                        cur[4] += wb[0]; cur[5] += wb[1]; cur[6] += wb[2]; cur[7] += wb[3];
                    }
                }
            }

            unsigned nm = 0;
            #pragma unroll
            for (int u = 0; u < 8; ++u) {
                float sp = ((sm >> u) & 1u) ? 1.0f : 0.0f;
                v1[u] = 0.95f * v1[u] + 0.05f * cur[u] - sp;
                a1[u] = 0.85f * a1[u] + 0.15f * sp;
                if (v1[u] - (1.0f + 0.05f * a1[u]) > 0.0f) nm |= (1u << u);
            }

            unsigned long long anyb = __ballot(nm != 0u);
            float io = 0.0f;
            if (anyb) {              // rare path: readout current from spikes
                #pragma unroll
                for (int u = 0; u < 8; ++u) {
                    unsigned long long mu = __ballot((nm >> u) & 1u);
                    while (mu) {
                        int jl = __ffsll(mu) - 1; mu &= mu - 1;
                        int unit = jl * 8 + u;
                        if (lane < NOUT) io += w_out[(size_t)lane * NHID + unit];
                    }
                }
            }

            v_out = 0.9f * v_out + io;
            float so = (v_out - 1.0f > 0.0f) ? 1.0f : 0.0f;
            v_out -= so;
            acco += v_out;

            sm = nm;
            anyprev = (anyb != 0ull);
        }
    }

    if (lane < NOUT) out[b * NOUT + lane] = acco * (1.0f / 250.0f);
}

// ---------------- launcher ----------------
extern "C" void kernel_launch(void* const* d_in, const int* in_sizes, int n_in,
                              void* d_out, int out_size, void* d_ws, size_t ws_size,
                              hipStream_t stream)
{
    const float* x     = (const float*)d_in[0];
    const float* w_kan = (const float*)d_in[1];
    const float* d1    = (const float*)d_in[2];
    const float* d2    = (const float*)d_in[3];
    const float* d3    = (const float*)d_in[4];
    const float* w_rec = (const float*)d_in[5];
    const float* w_out = (const float*)d_in[6];
    float* out = (float*)d_out;

    char*   ws    = (char*)d_ws;
    __bf16* iin   = (__bf16*)ws;
    int*    Bpack = (int*)(ws + BPACK_OFF);
    float*  wrecT = (float*)(ws + WRECT_OFF);

    kan_pack<<<dim3((BPACK_WORDS + 255) / 256), 256, 0, stream>>>(
        w_kan, d1, d2, d3, w_rec, Bpack, wrecT);
    kan_gemm<<<dim3(M_TOT / 128), 512, 0, stream>>>(x, Bpack, iin);
    kan_scan<<<dim3(B_), 64, 0, stream>>>(iin, wrecT, w_out, out);
}